// Round 8
// baseline (5850.588 us; speedup 1.0000x reference)
//
#include <hip/hip_runtime.h>
#include <math.h>

#define T_LEN 1000
#define BATCH 16
#define MEL   80
#define HID   512
#define NCLS  64
#define SL    8        // blocks per chain (8 x 512 threads) — register-feasible geometry

__device__ __forceinline__ float fast_tanh(float x) {
    float e = __expf(2.0f * x);
    return 1.0f - 2.0f / (e + 1.0f);
}
__device__ __forceinline__ float fast_sigmoid(float x) {
    return 1.0f / (1.0f + __expf(-x));
}

// packed (value, epoch) 8B atom. Published via __hip_atomic_store AGENT
// (proven). Detection is now decoupled from data: per-wave 8B TAILS published
// after a wave-local vmcnt drain; consumers poll tails (512B/round, wave-0
// only) instead of sweeping the 32KB pair set every round (r1-r6's hidden
// cost: 4MB/round chip-wide LLC churn). The data gather runs ONCE, through
// the r6-proven one-wait asm path with epoch-verify + atomic fallback, so
// tails are only a hint — correctness never depends on them.
__device__ __forceinline__ unsigned long long pack_pair(float v, unsigned e) {
    return ((unsigned long long)e << 32) | (unsigned long long)__float_as_uint(v);
}
__device__ __forceinline__ float pair_val(unsigned long long p) {
    return __uint_as_float((unsigned)(p & 0xffffffffull));
}
__device__ __forceinline__ unsigned pair_epoch(unsigned long long p) {
    return (unsigned)(p >> 32);
}

// one-shot LLC bulk load of 64 CONTIGUOUS floats (asm-defined => cannot be
// rematerialized => register-resident). NOT used in any spin loop.
__device__ __forceinline__ void llc_load16c(const float* base, float4 (&r)[16]) {
    asm volatile(
        "global_load_dwordx4 %0, %16, off sc0 sc1\n\t"
        "global_load_dwordx4 %1, %16, off offset:16 sc0 sc1\n\t"
        "global_load_dwordx4 %2, %16, off offset:32 sc0 sc1\n\t"
        "global_load_dwordx4 %3, %16, off offset:48 sc0 sc1\n\t"
        "global_load_dwordx4 %4, %16, off offset:64 sc0 sc1\n\t"
        "global_load_dwordx4 %5, %16, off offset:80 sc0 sc1\n\t"
        "global_load_dwordx4 %6, %16, off offset:96 sc0 sc1\n\t"
        "global_load_dwordx4 %7, %16, off offset:112 sc0 sc1\n\t"
        "global_load_dwordx4 %8, %16, off offset:128 sc0 sc1\n\t"
        "global_load_dwordx4 %9, %16, off offset:144 sc0 sc1\n\t"
        "global_load_dwordx4 %10, %16, off offset:160 sc0 sc1\n\t"
        "global_load_dwordx4 %11, %16, off offset:176 sc0 sc1\n\t"
        "global_load_dwordx4 %12, %16, off offset:192 sc0 sc1\n\t"
        "global_load_dwordx4 %13, %16, off offset:208 sc0 sc1\n\t"
        "global_load_dwordx4 %14, %16, off offset:224 sc0 sc1\n\t"
        "global_load_dwordx4 %15, %16, off offset:240 sc0 sc1\n\t"
        "s_waitcnt vmcnt(0)"
        : "=&v"(r[0]), "=&v"(r[1]), "=&v"(r[2]), "=&v"(r[3]),
          "=&v"(r[4]), "=&v"(r[5]), "=&v"(r[6]), "=&v"(r[7]),
          "=&v"(r[8]), "=&v"(r[9]), "=&v"(r[10]), "=&v"(r[11]),
          "=&v"(r[12]), "=&v"(r[13]), "=&v"(r[14]), "=&v"(r[15])
        : "v"(base)
        : "memory");
}

// K0: init pair buffer + tails to epoch 0 (never matches poll targets >= 1).
#define PART_WORDS (BATCH * 2 * SL * HID)
#define TAIL_WORDS (BATCH * 2 * SL * 8)
#define INIT_WORDS (PART_WORDS + TAIL_WORDS)
__global__ void k0_init(unsigned long long* part) {
    int i = blockIdx.x * 256 + threadIdx.x;
    if (i < INIT_WORDS) part[i] = 0ull;
}

// K1: per t: x_norm0 from feats, be0 = x_norm0 @ B0^T
__global__ __launch_bounds__(256) void k1_be0(const float* __restrict__ feats,
                                              const float* __restrict__ B0,
                                              float* __restrict__ be0) {
    const int t = blockIdx.x;
    const int tid = threadIdx.x;
    __shared__ float xf[BATCH][MEL];
    __shared__ float sc[BATCH];
    for (int idx = tid; idx < BATCH * MEL; idx += 256) {
        int b = idx / MEL, m = idx % MEL;
        xf[b][m] = feats[b * (T_LEN * MEL) + t * MEL + m];
    }
    __syncthreads();
    if (tid < BATCH) {
        float ss = 0.f;
        for (int m = 0; m < MEL; ++m) { float v = xf[tid][m]; ss += v * v; }
        sc[tid] = fmaxf(sqrtf(ss), 1e-6f);
    }
    __syncthreads();
    for (int idx = tid; idx < BATCH * MEL; idx += 256) {
        int b = idx / MEL, m = idx % MEL;
        float v = xf[b][m] / sc[b];
        xf[b][m] = fminf(fmaxf(v, -1.f), 1.f);
    }
    __syncthreads();
    for (int j = tid; j < HID; j += 256) {
        float acc[BATCH];
        #pragma unroll
        for (int b = 0; b < BATCH; ++b) acc[b] = 0.f;
        const float* brow = B0 + j * MEL;
        for (int k = 0; k < MEL; k += 4) {
            float4 w = *(const float4*)(brow + k);
            #pragma unroll
            for (int b = 0; b < BATCH; ++b) {
                float4 xv = *(const float4*)(&xf[b][k]);
                acc[b] += w.x * xv.x + w.y * xv.y + w.z * xv.z + w.w * xv.w;
            }
        }
        #pragma unroll
        for (int b = 0; b < BATCH; ++b)
            be0[(t * BATCH + b) * HID + j] = acc[b];
    }
}

// K2: per t: x_norm1 from be0, be1 = x_norm1 @ B1^T, store xs1 (r1-proven)
__global__ __launch_bounds__(256) void k2_be1(const float* __restrict__ be0,
                                              const float* __restrict__ B1,
                                              float* __restrict__ be1,
                                              float* __restrict__ xs1) {
    const int t = blockIdx.x;
    const int tid = threadIdx.x;
    __shared__ float xn[BATCH][HID];
    __shared__ float sc[BATCH];
    __shared__ float psum[BATCH][16];
    for (int idx = tid; idx < BATCH * HID; idx += 256) {
        int b = idx >> 9, k = idx & 511;
        xn[b][k] = be0[(t * BATCH + b) * HID + k];
    }
    __syncthreads();
    {
        int b = tid >> 4, l = tid & 15;
        float ss = 0.f;
        for (int k = l; k < HID; k += 16) { float v = xn[b][k]; ss += v * v; }
        psum[b][l] = ss;
    }
    __syncthreads();
    if (tid < BATCH) {
        float ss = 0.f;
        #pragma unroll
        for (int l = 0; l < 16; ++l) ss += psum[tid][l];
        float s = fmaxf(sqrtf(ss), 1e-6f);
        sc[tid] = s;
        xs1[t * BATCH + tid] = s;
    }
    __syncthreads();
    for (int idx = tid; idx < BATCH * HID; idx += 256) {
        int b = idx >> 9, k = idx & 511;
        float v = xn[b][k] / sc[b];
        xn[b][k] = fminf(fmaxf(v, -1.f), 1.f);
    }
    __syncthreads();
    for (int j = tid; j < HID; j += 256) {
        float acc[BATCH];
        #pragma unroll
        for (int b = 0; b < BATCH; ++b) acc[b] = 0.f;
        const float* brow = B1 + j * HID;
        for (int k = 0; k < HID; k += 4) {
            float4 w = *(const float4*)(brow + k);
            #pragma unroll
            for (int b = 0; b < BATCH; ++b) {
                float4 xv = *(const float4*)(&xn[b][k]);
                acc[b] += w.x * xv.x + w.y * xv.y + w.z * xv.z + w.w * xv.w;
            }
        }
        #pragma unroll
        for (int b = 0; b < BATCH; ++b)
            be1[(t * BATCH + b) * HID + j] = acc[b];
    }
}

// K3: sequential recurrence, ONE exchange per step (r1 structure + layout),
// tail-hinted detection:
//   Producers: publish 512 pairs slice-major (single producer per line),
//     per-wave vmcnt drain, lane0 publishes one 8B tail per wave. Tails are
//     slice-major at 64B stride => each producer's tails own a private line.
//   Consumers: wave 0 polls the chain's 64 tails (512B/round — 64x lighter
//     than sweeping pairs), barrier, then ALL threads gather their row's 8
//     pairs ONCE via the r6-proven one-wait asm loop (epoch-verified, with
//     atomic-gather fallback). Correctness never depends on tails.
__global__ __launch_bounds__(512, 1) void k3_fused(
    const float* __restrict__ be0, const float* __restrict__ be1,
    const float* __restrict__ xs1,
    const float* __restrict__ C1, const float* __restrict__ W1,
    const float* __restrict__ a1, const float* __restrict__ tau,
    const float* __restrict__ gam,
    float* __restrict__ h1s,
    unsigned long long* part)
{
    const int chain = blockIdx.x & 15;
    const int slice = blockIdx.x >> 4;        // 0..7
    const int tid = threadIdx.x;              // 0..511 ; phase-1 row = tid
    const int w = tid >> 6;                   // wave 0..7
    const int lane = tid & 63;
    const int jq = tid >> 3;                  // phase-2 column within slice 0..63
    const int kc = tid & 7;                   // phase-2 k-chunk 0..7
    const int j2 = slice * 64 + jq;           // phase-2 global output column
    const bool lead = (kc == 0);

    unsigned long long* tails = part + PART_WORDS;   // [B][2][SL][8]

    // 32 float4 = 128 regs of weights, asm-defined => register-resident
    float4 wC[16], wW[16];
    llc_load16c(C1 + (size_t)tid * HID + slice * 64, wC);
    llc_load16c(W1 + (size_t)j2 * HID + kc * 64, wW);

    const float tauv = tau[0], gamv = gam[0];
    const float siga = fast_sigmoid(a1[j2]);

    unsigned long long* pc = part + (size_t)chain * (2 * SL * HID);
    unsigned long long* tc = tails + (size_t)chain * (2 * SL * 8);

    __shared__ float h_s[64];                      // own h slice (broadcast reads)
    __shared__ __align__(16) float e_s[HID + 32];  // err, padded per 64-chunk
    __shared__ float sq_s[8];

    float hj = 0.f;                           // lead lanes: h for column j2
    if (tid < 64) h_s[tid] = 0.f;

    // t=0 streams
    float cur_be0 = be0[(size_t)chain * HID + tid];
    float cur_be1 = 0.f;
    if (lead) cur_be1 = __builtin_nontemporal_load(&be1[(size_t)chain * HID + j2]);
    float cur_xs = xs1[chain];
    __syncthreads();

    for (int t = 0; t < T_LEN; ++t) {
        const unsigned tag = (unsigned)(t + 1);
        unsigned long long* ps = pc + (size_t)(t & 1) * (SL * HID);
        unsigned long long* ts = tc + (size_t)(t & 1) * (SL * 8);

        // ---- phase 1: 64-MAC partial of dp[tid] over own h slice ----
        {
            float p0 = 0.f, p1 = 0.f, p2 = 0.f, p3 = 0.f;
            #pragma unroll
            for (int i = 0; i < 16; ++i) {
                float4 hv = *(const float4*)(h_s + 4 * i);   // broadcast, no conflict
                p0 += wC[i].x * hv.x; p1 += wC[i].y * hv.y;
                p2 += wC[i].z * hv.z; p3 += wC[i].w * hv.w;
            }
            float pp = (p0 + p1) + (p2 + p3);
            __hip_atomic_store(&ps[slice * HID + tid], pack_pair(pp, tag),
                               __ATOMIC_RELAXED, __HIP_MEMORY_SCOPE_AGENT);
        }
        // per-wave drain of the 64 value stores, then one tail per wave.
        asm volatile("s_waitcnt vmcnt(0)" ::: "memory");
        if (lane == 0)
            __hip_atomic_store(&ts[slice * 8 + w], (unsigned long long)tag,
                               __ATOMIC_RELAXED, __HIP_MEMORY_SCOPE_AGENT);

        // prefetch next step's streams (after the drain so it never blocks the
        // tail publish; flies during the tail poll)
        float nxt_be0 = 0.f, nxt_be1 = 0.f, nxt_xs = 0.f;
        if (t + 1 < T_LEN) {
            const size_t nrow = (size_t)((t + 1) * BATCH + chain) * HID;
            nxt_be0 = be0[nrow + tid];
            if (lead) nxt_be1 = __builtin_nontemporal_load(&be1[nrow + j2]);
            nxt_xs = xs1[(t + 1) * BATCH + chain];
        }

        // ---- tail poll: wave 0 only, one 8B load per lane (512B/round) ----
        if (w == 0) {
            const unsigned long long* tp = ts + lane;   // lane = slice*8 + wave
            for (;;) {
                unsigned long long tv = __hip_atomic_load(tp, __ATOMIC_RELAXED,
                                                          __HIP_MEMORY_SCOPE_AGENT);
                if (__all(tv == (unsigned long long)tag)) break;
                __builtin_amdgcn_s_sleep(1);
            }
        }
        __syncthreads();   // all producers' pairs are published (per tails)

        // ---- gather: row tid's 8 pairs ONCE (epoch-verified, r6-proven) ----
        float dp;
        {
            const unsigned long long* a0 = ps + 0 * HID + tid;
            const unsigned long long* a1p = ps + 1 * HID + tid;
            const unsigned long long* a2 = ps + 2 * HID + tid;
            const unsigned long long* a3 = ps + 3 * HID + tid;
            const unsigned long long* a4 = ps + 4 * HID + tid;
            const unsigned long long* a5 = ps + 5 * HID + tid;
            const unsigned long long* a6 = ps + 6 * HID + tid;
            const unsigned long long* a7 = ps + 7 * HID + tid;
            unsigned long long q0, q1, q2, q3, q4, q5, q6, q7;
            int rounds = 0;
            for (;;) {
                asm volatile(
                    "global_load_dwordx2 %0, %8, off sc0 sc1\n\t"
                    "global_load_dwordx2 %1, %9, off sc0 sc1\n\t"
                    "global_load_dwordx2 %2, %10, off sc0 sc1\n\t"
                    "global_load_dwordx2 %3, %11, off sc0 sc1\n\t"
                    "global_load_dwordx2 %4, %12, off sc0 sc1\n\t"
                    "global_load_dwordx2 %5, %13, off sc0 sc1\n\t"
                    "global_load_dwordx2 %6, %14, off sc0 sc1\n\t"
                    "global_load_dwordx2 %7, %15, off sc0 sc1\n\t"
                    "s_waitcnt vmcnt(0)"
                    : "=&v"(q0), "=&v"(q1), "=&v"(q2), "=&v"(q3),
                      "=&v"(q4), "=&v"(q5), "=&v"(q6), "=&v"(q7)
                    : "v"(a0), "v"(a1p), "v"(a2), "v"(a3),
                      "v"(a4), "v"(a5), "v"(a6), "v"(a7)
                    : "memory");
                bool ok = (pair_epoch(q0) == tag) & (pair_epoch(q1) == tag)
                        & (pair_epoch(q2) == tag) & (pair_epoch(q3) == tag)
                        & (pair_epoch(q4) == tag) & (pair_epoch(q5) == tag)
                        & (pair_epoch(q6) == tag) & (pair_epoch(q7) == tag);
                if (__all(ok)) break;
                // guaranteed-progress fallback: proven atomic gather
                if (++rounds > 200000) {
                    q0 = __hip_atomic_load(a0, __ATOMIC_RELAXED, __HIP_MEMORY_SCOPE_AGENT);
                    q1 = __hip_atomic_load(a1p, __ATOMIC_RELAXED, __HIP_MEMORY_SCOPE_AGENT);
                    q2 = __hip_atomic_load(a2, __ATOMIC_RELAXED, __HIP_MEMORY_SCOPE_AGENT);
                    q3 = __hip_atomic_load(a3, __ATOMIC_RELAXED, __HIP_MEMORY_SCOPE_AGENT);
                    q4 = __hip_atomic_load(a4, __ATOMIC_RELAXED, __HIP_MEMORY_SCOPE_AGENT);
                    q5 = __hip_atomic_load(a5, __ATOMIC_RELAXED, __HIP_MEMORY_SCOPE_AGENT);
                    q6 = __hip_atomic_load(a6, __ATOMIC_RELAXED, __HIP_MEMORY_SCOPE_AGENT);
                    q7 = __hip_atomic_load(a7, __ATOMIC_RELAXED, __HIP_MEMORY_SCOPE_AGENT);
                    bool ok2 = (pair_epoch(q0) == tag) & (pair_epoch(q1) == tag)
                             & (pair_epoch(q2) == tag) & (pair_epoch(q3) == tag)
                             & (pair_epoch(q4) == tag) & (pair_epoch(q5) == tag)
                             & (pair_epoch(q6) == tag) & (pair_epoch(q7) == tag);
                    if (__all(ok2)) break;
                    rounds = 0;
                }
                __builtin_amdgcn_s_sleep(1);
            }
            dp = ((pair_val(q0) + pair_val(q1)) + (pair_val(q2) + pair_val(q3)))
               + ((pair_val(q4) + pair_val(q5)) + (pair_val(q6) + pair_val(q7)));
        }

        // ---- err vector; stage padded for conflict-free phase 2 ----
        {
            float err = cur_be0 - fast_tanh(dp) * cur_xs;
            e_s[tid + (tid >> 6) * 4] = err;
            float sq = err * err;
            #pragma unroll
            for (int off = 32; off > 0; off >>= 1) sq += __shfl_down(sq, off, 64);
            if (lane == 0) sq_s[w] = sq;
        }
        __syncthreads();   // e_s + sq_s complete

        // ---- phase 2: ee = (err @ W1^T)[j2] over k-chunk, gated update ----
        {
            float ssT = ((sq_s[0] + sq_s[1]) + (sq_s[2] + sq_s[3]))
                      + ((sq_s[4] + sq_s[5]) + (sq_s[6] + sq_s[7]));
            const float* esb = e_s + kc * 68;
            float q0 = 0.f, q1 = 0.f, q2 = 0.f, q3 = 0.f;
            #pragma unroll
            for (int i = 0; i < 16; ++i) {
                float4 ev = *(const float4*)(esb + 4 * i);   // 8 groups x 16B = 32 banks
                q0 += wW[i].x * ev.x; q1 += wW[i].y * ev.y;
                q2 += wW[i].z * ev.z; q3 += wW[i].w * ev.w;
            }
            float ee = (q0 + q1) + (q2 + q3);
            ee += __shfl_down(ee, 4, 8);
            ee += __shfl_down(ee, 2, 8);
            ee += __shfl_down(ee, 1, 8);
            if (lead) {
                float rel = fminf(sqrtf(ssT) / cur_xs, 4.0f);
                float s = fast_sigmoid((rel - tauv) / gamv);
                float input_h = hj * 0.2f + cur_be1 * 0.6f + ee * s * 0.2f;
                float g = s * siga;
                hj = hj * (1.f - g) + fast_tanh(input_h) * g;
                h_s[jq] = hj;
                __builtin_nontemporal_store(hj,
                    &h1s[(size_t)(t * BATCH + chain) * HID + j2]);
            }
        }
        __syncthreads();   // h_s ready for next step; e_s reads done

        cur_be0 = nxt_be0; cur_be1 = nxt_be1; cur_xs = nxt_xs;
    }
}

// K4: head matmul out[b,t,c] = [h1 || be1] @ head_w^T + head_b
__global__ __launch_bounds__(1024) void k4_head(const float* __restrict__ h1s,
                                                const float* __restrict__ be1,
                                                const float* __restrict__ head_w,
                                                const float* __restrict__ head_b,
                                                float* __restrict__ out) {
    const int t = blockIdx.x;
    const int tid = threadIdx.x;
    const int c = tid >> 4;
    const int b = tid & 15;
    const float* hw = head_w + c * (2 * HID);
    const float* x1 = h1s + (size_t)(t * BATCH + b) * HID;
    const float* x2 = be1 + (size_t)(t * BATCH + b) * HID;
    float acc0 = head_b[c], acc1 = 0.f;
    for (int k = 0; k < HID; k += 4) {
        float4 w = *(const float4*)(hw + k);
        float4 xv = *(const float4*)(x1 + k);
        acc0 += w.x * xv.x + w.y * xv.y + w.z * xv.z + w.w * xv.w;
    }
    for (int k = 0; k < HID; k += 4) {
        float4 w = *(const float4*)(hw + HID + k);
        float4 xv = *(const float4*)(x2 + k);
        acc1 += w.x * xv.x + w.y * xv.y + w.z * xv.z + w.w * xv.w;
    }
    out[b * (T_LEN * NCLS) + t * NCLS + c] = acc0 + acc1;
}

extern "C" void kernel_launch(void* const* d_in, const int* in_sizes, int n_in,
                              void* d_out, int out_size, void* d_ws, size_t ws_size,
                              hipStream_t stream) {
    const float* feats  = (const float*)d_in[0];
    const float* B0     = (const float*)d_in[2];
    const float* C1     = (const float*)d_in[7];
    const float* B1     = (const float*)d_in[8];
    const float* W1     = (const float*)d_in[9];
    const float* a1     = (const float*)d_in[10];
    const float* tau1   = (const float*)d_in[11];
    const float* gam1   = (const float*)d_in[12];
    const float* head_w = (const float*)d_in[13];
    const float* head_b = (const float*)d_in[14];
    float* out = (float*)d_out;

    float* be0 = (float*)d_ws;                          // T*B*HID
    float* be1 = be0 + (size_t)T_LEN * BATCH * HID;     // T*B*HID
    float* xs1 = be1 + (size_t)T_LEN * BATCH * HID;     // T*B
    float* h1s = xs1 + (size_t)T_LEN * BATCH;           // T*B*HID
    unsigned long long* part =
        (unsigned long long*)(h1s + (size_t)T_LEN * BATCH * HID);
    // part layout: pairs [B*2*SL*HID] | tails [B*2*SL*8]

    hipLaunchKernelGGL(k0_init, dim3((INIT_WORDS + 255) / 256), dim3(256), 0,
                       stream, part);
    hipLaunchKernelGGL(k1_be0, dim3(T_LEN), dim3(256), 0, stream, feats, B0, be0);
    hipLaunchKernelGGL(k2_be1, dim3(T_LEN), dim3(256), 0, stream, be0, B1, be1, xs1);
    hipLaunchKernelGGL(k3_fused, dim3(BATCH * SL), dim3(512), 0, stream,
                       be0, be1, xs1, C1, W1, a1, tau1, gam1, h1s, part);
    hipLaunchKernelGGL(k4_head, dim3(T_LEN), dim3(1024), 0, stream,
                       h1s, be1, head_w, head_b, out);
}

// Round 9
// 3927.534 us; speedup vs baseline: 1.4896x; 1.4896x over previous
//
#include <hip/hip_runtime.h>
#include <math.h>

#define T_LEN 1000
#define BATCH 16
#define MEL   80
#define HID   512
#define NCLS  64
#define SL    8        // blocks per chain (8 x 512 threads) — register-feasible geometry

__device__ __forceinline__ float fast_tanh(float x) {
    float e = __expf(2.0f * x);
    return 1.0f - 2.0f / (e + 1.0f);
}
__device__ __forceinline__ float fast_sigmoid(float x) {
    return 1.0f / (1.0f + __expf(-x));
}

// packed (value, epoch) 8B atom. Published via __hip_atomic_store AGENT,
// polled via the r6-proven one-wait asm gather (fused data+validity in ONE
// load stage). Exchange ledger: serialized loads (r4) = n.s., one-wait (r6)
// = n.s., flags (r3) / interleaved lines (r5) / tails (r8) = all WORSE.
// => the floor is store->LLC visibility + detect RT; we now fill that wait
// window with useful local work (be1 computation) instead of shaving it.
__device__ __forceinline__ unsigned long long pack_pair(float v, unsigned e) {
    return ((unsigned long long)e << 32) | (unsigned long long)__float_as_uint(v);
}
__device__ __forceinline__ float pair_val(unsigned long long p) {
    return __uint_as_float((unsigned)(p & 0xffffffffull));
}
__device__ __forceinline__ unsigned pair_epoch(unsigned long long p) {
    return (unsigned)(p >> 32);
}

// one-shot LLC bulk load of 64 CONTIGUOUS floats (asm-defined => cannot be
// rematerialized => register-resident). NOT used in any spin loop.
__device__ __forceinline__ void llc_load16c(const float* base, float4 (&r)[16]) {
    asm volatile(
        "global_load_dwordx4 %0, %16, off sc0 sc1\n\t"
        "global_load_dwordx4 %1, %16, off offset:16 sc0 sc1\n\t"
        "global_load_dwordx4 %2, %16, off offset:32 sc0 sc1\n\t"
        "global_load_dwordx4 %3, %16, off offset:48 sc0 sc1\n\t"
        "global_load_dwordx4 %4, %16, off offset:64 sc0 sc1\n\t"
        "global_load_dwordx4 %5, %16, off offset:80 sc0 sc1\n\t"
        "global_load_dwordx4 %6, %16, off offset:96 sc0 sc1\n\t"
        "global_load_dwordx4 %7, %16, off offset:112 sc0 sc1\n\t"
        "global_load_dwordx4 %8, %16, off offset:128 sc0 sc1\n\t"
        "global_load_dwordx4 %9, %16, off offset:144 sc0 sc1\n\t"
        "global_load_dwordx4 %10, %16, off offset:160 sc0 sc1\n\t"
        "global_load_dwordx4 %11, %16, off offset:176 sc0 sc1\n\t"
        "global_load_dwordx4 %12, %16, off offset:192 sc0 sc1\n\t"
        "global_load_dwordx4 %13, %16, off offset:208 sc0 sc1\n\t"
        "global_load_dwordx4 %14, %16, off offset:224 sc0 sc1\n\t"
        "global_load_dwordx4 %15, %16, off offset:240 sc0 sc1\n\t"
        "s_waitcnt vmcnt(0)"
        : "=&v"(r[0]), "=&v"(r[1]), "=&v"(r[2]), "=&v"(r[3]),
          "=&v"(r[4]), "=&v"(r[5]), "=&v"(r[6]), "=&v"(r[7]),
          "=&v"(r[8]), "=&v"(r[9]), "=&v"(r[10]), "=&v"(r[11]),
          "=&v"(r[12]), "=&v"(r[13]), "=&v"(r[14]), "=&v"(r[15])
        : "v"(base)
        : "memory");
}

// K0: init pair buffer to epoch 0 (never matches poll targets >= 1).
#define PART_WORDS (BATCH * 2 * SL * HID)
__global__ void k0_init(unsigned long long* part) {
    int i = blockIdx.x * 256 + threadIdx.x;
    if (i < PART_WORDS) part[i] = 0ull;
}

// K1: per t: x_norm0 from feats, be0 = x_norm0 @ B0^T
__global__ __launch_bounds__(256) void k1_be0(const float* __restrict__ feats,
                                              const float* __restrict__ B0,
                                              float* __restrict__ be0) {
    const int t = blockIdx.x;
    const int tid = threadIdx.x;
    __shared__ float xf[BATCH][MEL];
    __shared__ float sc[BATCH];
    for (int idx = tid; idx < BATCH * MEL; idx += 256) {
        int b = idx / MEL, m = idx % MEL;
        xf[b][m] = feats[b * (T_LEN * MEL) + t * MEL + m];
    }
    __syncthreads();
    if (tid < BATCH) {
        float ss = 0.f;
        for (int m = 0; m < MEL; ++m) { float v = xf[tid][m]; ss += v * v; }
        sc[tid] = fmaxf(sqrtf(ss), 1e-6f);
    }
    __syncthreads();
    for (int idx = tid; idx < BATCH * MEL; idx += 256) {
        int b = idx / MEL, m = idx % MEL;
        float v = xf[b][m] / sc[b];
        xf[b][m] = fminf(fmaxf(v, -1.f), 1.f);
    }
    __syncthreads();
    for (int j = tid; j < HID; j += 256) {
        float acc[BATCH];
        #pragma unroll
        for (int b = 0; b < BATCH; ++b) acc[b] = 0.f;
        const float* brow = B0 + j * MEL;
        for (int k = 0; k < MEL; k += 4) {
            float4 w = *(const float4*)(brow + k);
            #pragma unroll
            for (int b = 0; b < BATCH; ++b) {
                float4 xv = *(const float4*)(&xf[b][k]);
                acc[b] += w.x * xv.x + w.y * xv.y + w.z * xv.z + w.w * xv.w;
            }
        }
        #pragma unroll
        for (int b = 0; b < BATCH; ++b)
            be0[(t * BATCH + b) * HID + j] = acc[b];
    }
}

// K3: sequential recurrence, ONE exchange per step (r6-proven exchange) with
// be1/xs FUSED into the publish->poll slack window (k2 deleted):
//   Block s owns h slice [64s,64s+64). Phase 1 (k-split) publishes 512
//   partial-dp pairs slice-major. While those flow to the LLC, the block
//   computes be1(t+1) = clip(be0(t+1)/||be0||) @ B1^T for its 64 columns —
//   pure local work (stage row in LDS, normalize, 16 f4 MACs, width-8
//   reduce, lead stores to be1 global for k4). Then the poll+gather runs
//   (one-wait asm, epoch-verified, atomic fallback). Phase 2 j-split local.
__global__ __launch_bounds__(512, 1) void k3_fused(
    const float* __restrict__ be0g,
    const float* __restrict__ C1, const float* __restrict__ W1,
    const float* __restrict__ B1,
    const float* __restrict__ a1, const float* __restrict__ tau,
    const float* __restrict__ gam,
    float* __restrict__ be1g, float* __restrict__ h1s,
    unsigned long long* part)
{
    const int chain = blockIdx.x & 15;
    const int slice = blockIdx.x >> 4;        // 0..7
    const int tid = threadIdx.x;              // 0..511 ; phase-1 row = tid
    const int w = tid >> 6;                   // wave 0..7
    const int lane = tid & 63;
    const int jq = tid >> 3;                  // phase-2 column within slice 0..63
    const int kc = tid & 7;                   // phase-2 k-chunk 0..7
    const int j2 = slice * 64 + jq;           // phase-2 global output column
    const bool lead = (kc == 0);

    // 48 float4 = 192 regs of weights, asm-defined => register-resident
    // phase-1: C1[row=tid, 64*slice..+64)  phase-2: W1[j2, 64*kc..+64)
    // be1:     B1[j2, 64*kc..+64)
    float4 wC[16], wW[16], wB[16];
    llc_load16c(C1 + (size_t)tid * HID + slice * 64, wC);
    llc_load16c(W1 + (size_t)j2 * HID + kc * 64, wW);
    llc_load16c(B1 + (size_t)j2 * HID + kc * 64, wB);

    const float tauv = tau[0], gamv = gam[0];
    const float siga = fast_sigmoid(a1[j2]);

    unsigned long long* pc = part + (size_t)chain * (2 * SL * HID);

    __shared__ float h_s[64];                      // own h slice (broadcast reads)
    __shared__ __align__(16) float e_s[HID + 32];  // err, padded per 64-chunk
    __shared__ __align__(16) float x_s[HID + 32];  // normalized be0 row, padded
    __shared__ float sq_s[8];
    __shared__ float xsq_s[8];

    float hj = 0.f;                           // lead lanes: h for column j2
    if (tid < 64) h_s[tid] = 0.f;

    // ---- prologue: t=0 streams; compute cur_xs, cur_be1 locally ----
    float cur_be0 = be0g[(size_t)chain * HID + tid];
    float cur_xs, cur_be1 = 0.f;
    {
        float sq = cur_be0 * cur_be0;
        #pragma unroll
        for (int off = 32; off > 0; off >>= 1) sq += __shfl_down(sq, off, 64);
        if (lane == 0) xsq_s[w] = sq;
        __syncthreads();
        float ssX = ((xsq_s[0] + xsq_s[1]) + (xsq_s[2] + xsq_s[3]))
                  + ((xsq_s[4] + xsq_s[5]) + (xsq_s[6] + xsq_s[7]));
        cur_xs = fmaxf(sqrtf(ssX), 1e-6f);
        float xn = cur_be0 / cur_xs;
        x_s[tid + (tid >> 6) * 4] = fminf(fmaxf(xn, -1.f), 1.f);
        __syncthreads();
        const float* xb = x_s + kc * 68;
        float q0 = 0.f, q1 = 0.f, q2 = 0.f, q3 = 0.f;
        #pragma unroll
        for (int i = 0; i < 16; ++i) {
            float4 v4 = *(const float4*)(xb + 4 * i);
            q0 += wB[i].x * v4.x; q1 += wB[i].y * v4.y;
            q2 += wB[i].z * v4.z; q3 += wB[i].w * v4.w;
        }
        float bq = (q0 + q1) + (q2 + q3);
        bq += __shfl_down(bq, 4, 8);
        bq += __shfl_down(bq, 2, 8);
        bq += __shfl_down(bq, 1, 8);
        if (lead) {
            cur_be1 = bq;
            __builtin_nontemporal_store(bq, &be1g[(size_t)chain * HID + j2]);
        }
        __syncthreads();   // x_s free; h_s visible
    }

    for (int t = 0; t < T_LEN; ++t) {
        // issue next-row stream early (consumed in the slack window)
        float nxt_be0 = 0.f;
        if (t + 1 < T_LEN)
            nxt_be0 = be0g[(size_t)((t + 1) * BATCH + chain) * HID + tid];
        const unsigned tag = (unsigned)(t + 1);
        unsigned long long* ps = pc + (size_t)(t & 1) * (SL * HID);

        // ---- phase 1: 64-MAC partial of dp[tid] over own h slice ----
        {
            float p0 = 0.f, p1 = 0.f, p2 = 0.f, p3 = 0.f;
            #pragma unroll
            for (int i = 0; i < 16; ++i) {
                float4 hv = *(const float4*)(h_s + 4 * i);   // broadcast, no conflict
                p0 += wC[i].x * hv.x; p1 += wC[i].y * hv.y;
                p2 += wC[i].z * hv.z; p3 += wC[i].w * hv.w;
            }
            float pp = (p0 + p1) + (p2 + p3);
            __hip_atomic_store(&ps[slice * HID + tid], pack_pair(pp, tag),
                               __ATOMIC_RELAXED, __HIP_MEMORY_SCOPE_AGENT);
        }

        // ---- slack window (partials in flight): be1(t+1) + xs(t+1), local ----
        float nxt_xs = 0.f, nxt_be1 = 0.f;
        if (t + 1 < T_LEN) {
            float sq = nxt_be0 * nxt_be0;
            #pragma unroll
            for (int off = 32; off > 0; off >>= 1) sq += __shfl_down(sq, off, 64);
            if (lane == 0) xsq_s[w] = sq;
            __syncthreads();
            float ssX = ((xsq_s[0] + xsq_s[1]) + (xsq_s[2] + xsq_s[3]))
                      + ((xsq_s[4] + xsq_s[5]) + (xsq_s[6] + xsq_s[7]));
            nxt_xs = fmaxf(sqrtf(ssX), 1e-6f);
            float xn = nxt_be0 / nxt_xs;
            x_s[tid + (tid >> 6) * 4] = fminf(fmaxf(xn, -1.f), 1.f);
            __syncthreads();
            const float* xb = x_s + kc * 68;
            float q0 = 0.f, q1 = 0.f, q2 = 0.f, q3 = 0.f;
            #pragma unroll
            for (int i = 0; i < 16; ++i) {
                float4 v4 = *(const float4*)(xb + 4 * i);
                q0 += wB[i].x * v4.x; q1 += wB[i].y * v4.y;
                q2 += wB[i].z * v4.z; q3 += wB[i].w * v4.w;
            }
            float bq = (q0 + q1) + (q2 + q3);
            bq += __shfl_down(bq, 4, 8);
            bq += __shfl_down(bq, 2, 8);
            bq += __shfl_down(bq, 1, 8);
            if (lead) {
                nxt_be1 = bq;
                __builtin_nontemporal_store(bq,
                    &be1g[(size_t)((t + 1) * BATCH + chain) * HID + j2]);
            }
        }

        // ---- poll: 8 single-producer pairs, ONE asm round-trip per round ----
        float dp;
        {
            const unsigned long long* a0 = ps + 0 * HID + tid;
            const unsigned long long* a1p = ps + 1 * HID + tid;
            const unsigned long long* a2 = ps + 2 * HID + tid;
            const unsigned long long* a3 = ps + 3 * HID + tid;
            const unsigned long long* a4 = ps + 4 * HID + tid;
            const unsigned long long* a5 = ps + 5 * HID + tid;
            const unsigned long long* a6 = ps + 6 * HID + tid;
            const unsigned long long* a7 = ps + 7 * HID + tid;
            unsigned long long q0, q1, q2, q3, q4, q5, q6, q7;
            int rounds = 0;
            for (;;) {
                asm volatile(
                    "global_load_dwordx2 %0, %8, off sc0 sc1\n\t"
                    "global_load_dwordx2 %1, %9, off sc0 sc1\n\t"
                    "global_load_dwordx2 %2, %10, off sc0 sc1\n\t"
                    "global_load_dwordx2 %3, %11, off sc0 sc1\n\t"
                    "global_load_dwordx2 %4, %12, off sc0 sc1\n\t"
                    "global_load_dwordx2 %5, %13, off sc0 sc1\n\t"
                    "global_load_dwordx2 %6, %14, off sc0 sc1\n\t"
                    "global_load_dwordx2 %7, %15, off sc0 sc1\n\t"
                    "s_waitcnt vmcnt(0)"
                    : "=&v"(q0), "=&v"(q1), "=&v"(q2), "=&v"(q3),
                      "=&v"(q4), "=&v"(q5), "=&v"(q6), "=&v"(q7)
                    : "v"(a0), "v"(a1p), "v"(a2), "v"(a3),
                      "v"(a4), "v"(a5), "v"(a6), "v"(a7)
                    : "memory");
                bool ok = (pair_epoch(q0) == tag) & (pair_epoch(q1) == tag)
                        & (pair_epoch(q2) == tag) & (pair_epoch(q3) == tag)
                        & (pair_epoch(q4) == tag) & (pair_epoch(q5) == tag)
                        & (pair_epoch(q6) == tag) & (pair_epoch(q7) == tag);
                if (__all(ok)) break;
                // guaranteed-progress fallback: proven atomic gather
                if (++rounds > 200000) {
                    q0 = __hip_atomic_load(a0, __ATOMIC_RELAXED, __HIP_MEMORY_SCOPE_AGENT);
                    q1 = __hip_atomic_load(a1p, __ATOMIC_RELAXED, __HIP_MEMORY_SCOPE_AGENT);
                    q2 = __hip_atomic_load(a2, __ATOMIC_RELAXED, __HIP_MEMORY_SCOPE_AGENT);
                    q3 = __hip_atomic_load(a3, __ATOMIC_RELAXED, __HIP_MEMORY_SCOPE_AGENT);
                    q4 = __hip_atomic_load(a4, __ATOMIC_RELAXED, __HIP_MEMORY_SCOPE_AGENT);
                    q5 = __hip_atomic_load(a5, __ATOMIC_RELAXED, __HIP_MEMORY_SCOPE_AGENT);
                    q6 = __hip_atomic_load(a6, __ATOMIC_RELAXED, __HIP_MEMORY_SCOPE_AGENT);
                    q7 = __hip_atomic_load(a7, __ATOMIC_RELAXED, __HIP_MEMORY_SCOPE_AGENT);
                    bool ok2 = (pair_epoch(q0) == tag) & (pair_epoch(q1) == tag)
                             & (pair_epoch(q2) == tag) & (pair_epoch(q3) == tag)
                             & (pair_epoch(q4) == tag) & (pair_epoch(q5) == tag)
                             & (pair_epoch(q6) == tag) & (pair_epoch(q7) == tag);
                    if (__all(ok2)) break;
                    rounds = 0;
                }
                __builtin_amdgcn_s_sleep(1);
            }
            dp = ((pair_val(q0) + pair_val(q1)) + (pair_val(q2) + pair_val(q3)))
               + ((pair_val(q4) + pair_val(q5)) + (pair_val(q6) + pair_val(q7)));
        }

        // ---- err vector; stage padded for conflict-free phase 2 ----
        {
            float err = cur_be0 - fast_tanh(dp) * cur_xs;
            e_s[tid + (tid >> 6) * 4] = err;
            float sq = err * err;
            #pragma unroll
            for (int off = 32; off > 0; off >>= 1) sq += __shfl_down(sq, off, 64);
            if (lane == 0) sq_s[w] = sq;
        }
        __syncthreads();   // e_s + sq_s complete

        // ---- phase 2: ee = (err @ W1^T)[j2] over k-chunk, gated update ----
        {
            float ssT = ((sq_s[0] + sq_s[1]) + (sq_s[2] + sq_s[3]))
                      + ((sq_s[4] + sq_s[5]) + (sq_s[6] + sq_s[7]));
            const float* esb = e_s + kc * 68;
            float q0 = 0.f, q1 = 0.f, q2 = 0.f, q3 = 0.f;
            #pragma unroll
            for (int i = 0; i < 16; ++i) {
                float4 ev = *(const float4*)(esb + 4 * i);   // 8 groups x 16B = 32 banks
                q0 += wW[i].x * ev.x; q1 += wW[i].y * ev.y;
                q2 += wW[i].z * ev.z; q3 += wW[i].w * ev.w;
            }
            float ee = (q0 + q1) + (q2 + q3);
            ee += __shfl_down(ee, 4, 8);
            ee += __shfl_down(ee, 2, 8);
            ee += __shfl_down(ee, 1, 8);
            if (lead) {
                float rel = fminf(sqrtf(ssT) / cur_xs, 4.0f);
                float s = fast_sigmoid((rel - tauv) / gamv);
                float input_h = hj * 0.2f + cur_be1 * 0.6f + ee * s * 0.2f;
                float g = s * siga;
                hj = hj * (1.f - g) + fast_tanh(input_h) * g;
                h_s[jq] = hj;
                __builtin_nontemporal_store(hj,
                    &h1s[(size_t)(t * BATCH + chain) * HID + j2]);
            }
        }
        __syncthreads();   // h_s ready for next step; e_s/x_s reads done

        cur_be0 = nxt_be0; cur_be1 = nxt_be1; cur_xs = nxt_xs;
    }
}

// K4: head matmul out[b,t,c] = [h1 || be1] @ head_w^T + head_b
__global__ __launch_bounds__(1024) void k4_head(const float* __restrict__ h1s,
                                                const float* __restrict__ be1,
                                                const float* __restrict__ head_w,
                                                const float* __restrict__ head_b,
                                                float* __restrict__ out) {
    const int t = blockIdx.x;
    const int tid = threadIdx.x;
    const int c = tid >> 4;
    const int b = tid & 15;
    const float* hw = head_w + c * (2 * HID);
    const float* x1 = h1s + (size_t)(t * BATCH + b) * HID;
    const float* x2 = be1 + (size_t)(t * BATCH + b) * HID;
    float acc0 = head_b[c], acc1 = 0.f;
    for (int k = 0; k < HID; k += 4) {
        float4 w = *(const float4*)(hw + k);
        float4 xv = *(const float4*)(x1 + k);
        acc0 += w.x * xv.x + w.y * xv.y + w.z * xv.z + w.w * xv.w;
    }
    for (int k = 0; k < HID; k += 4) {
        float4 w = *(const float4*)(hw + HID + k);
        float4 xv = *(const float4*)(x2 + k);
        acc1 += w.x * xv.x + w.y * xv.y + w.z * xv.z + w.w * xv.w;
    }
    out[b * (T_LEN * NCLS) + t * NCLS + c] = acc0 + acc1;
}

extern "C" void kernel_launch(void* const* d_in, const int* in_sizes, int n_in,
                              void* d_out, int out_size, void* d_ws, size_t ws_size,
                              hipStream_t stream) {
    const float* feats  = (const float*)d_in[0];
    const float* B0     = (const float*)d_in[2];
    const float* C1     = (const float*)d_in[7];
    const float* B1     = (const float*)d_in[8];
    const float* W1     = (const float*)d_in[9];
    const float* a1     = (const float*)d_in[10];
    const float* tau1   = (const float*)d_in[11];
    const float* gam1   = (const float*)d_in[12];
    const float* head_w = (const float*)d_in[13];
    const float* head_b = (const float*)d_in[14];
    float* out = (float*)d_out;

    float* be0 = (float*)d_ws;                          // T*B*HID
    float* be1 = be0 + (size_t)T_LEN * BATCH * HID;     // T*B*HID (k3-written)
    float* h1s = be1 + (size_t)T_LEN * BATCH * HID;     // T*B*HID
    unsigned long long* part =
        (unsigned long long*)(h1s + (size_t)T_LEN * BATCH * HID);  // PART_WORDS u64

    hipLaunchKernelGGL(k0_init, dim3(512), dim3(256), 0, stream, part);
    hipLaunchKernelGGL(k1_be0, dim3(T_LEN), dim3(256), 0, stream, feats, B0, be0);
    hipLaunchKernelGGL(k3_fused, dim3(BATCH * SL), dim3(512), 0, stream,
                       be0, C1, W1, B1, a1, tau1, gam1, be1, h1s, part);
    hipLaunchKernelGGL(k4_head, dim3(T_LEN), dim3(1024), 0, stream,
                       h1s, be1, head_w, head_b, out);
}